// Round 9
// baseline (159.584 us; speedup 1.0000x reference)
//
#include <hip/hip_runtime.h>
#include <cstdint>

#define N_ 4
#define L_ 8192
#define S_ 8192
#define H_ 8
#define D_ 64
#define E_ 64
#define HD_ 512       // H_*D_ row stride in floats
#define NH_ 32        // N_*H_
#define EPS_ 1e-6f
#define RS_ 68        // padded LDS row stride (floats) for p2 Q tile
#define TS_ 32        // s-rows per tile (p1)

__device__ __forceinline__ float elu1(float x) {
  return x > 0.0f ? x + 1.0f : __expf(x);
}

__device__ __forceinline__ void gl_lds_16B(const void* g, void* l) {
  __builtin_amdgcn_global_load_lds(
      (const __attribute__((address_space(1))) unsigned int*)g,
      (__attribute__((address_space(3))) unsigned int*)l, 16, 0, 0);
}

// cross-lane xor-reductions on the VALU (permlane*_swap), not the LDS pipe.
__device__ __forceinline__ float red16(float x) {
#if __has_builtin(__builtin_amdgcn_permlane16_swap)
  unsigned u = __float_as_uint(x);
  auto r = __builtin_amdgcn_permlane16_swap(u, u, false, false);
  return __uint_as_float((unsigned)r[0]) + __uint_as_float((unsigned)r[1]);
#else
  return x + __shfl_xor(x, 16, 64);
#endif
}
__device__ __forceinline__ float red32(float x) {
#if __has_builtin(__builtin_amdgcn_permlane32_swap)
  unsigned u = __float_as_uint(x);
  auto r = __builtin_amdgcn_permlane32_swap(u, u, false, false);
  return __uint_as_float((unsigned)r[0]) + __uint_as_float((unsigned)r[1]);
#else
  return x + __shfl_xor(x, 32, 64);
#endif
}

// ---------------- phase 1: partial KV/Ksum per block (NO atomics) -----------
// grid (C=32, H, N), block 512 (8 waves). LDS = fk 8KB (single, XOR-swizzled)
// + V 2x8KB = 24576 B. Two raw barriers/tile, NEVER vmcnt(0) in the loop:
//   A: elu+stage K(t) (auto-wait vmcnt leaves V(t)+newer in flight)
//   B: issue K(t+1) [regs] THEN V(t+1) [gl_lds -> buf (t+1)&1]
//   W1: lgkmcnt(0); s_barrier; vmcnt(2)  (V(t) landed; K/V(t+1) in flight)
//   C: compute tile t from fk + v[t&1]
//   W2: s_barrier only (protects fk rewrite + makes 2-deep V race-free:
//       all waves finish C(t) before any wave's B(t+1) targets buf t&1)
// Register diet vs R8: single fk (no ping-pong index), no vr/vw counters,
// 2-deep V indexed by t&1 -> steady live set ~52 regs < 64 budget (512,8).
__global__ __launch_bounds__(512, 8) void p1_kv(const float* __restrict__ keys,
                                                const float* __restrict__ values,
                                                float* __restrict__ pkv,
                                                float* __restrict__ pks,
                                                int tiles) {
  const int chunk = blockIdx.x, h = blockIdx.y, n = blockIdx.z;
  const int tid = threadIdx.x;
  const int w = tid >> 6, lane = tid & 63;
  const int sg = lane >> 4, eg = lane & 15;
  __shared__ float fk_lds[TS_ * 64];        // 8192 B, single, XOR-swizzled
  __shared__ float v_lds[2][TS_ * 64];      // 16384 B, 2-deep gl_lds dest

  const int srow = tid >> 4;                // 0..31 (also V src row)
  const int scol = (tid & 15) * 4;          // (also V src col)
  const int scolw = scol ^ ((srow & 3) << 3);   // swizzled fk write col
  const int dswz  = (w * 8) ^ (sg << 3);        // swizzled fk read base

  const float* Kb = keys   + (size_t)n * S_ * HD_ + h * D_;
  const float* Vb = values + (size_t)n * S_ * HD_ + h * D_;

  float acc[8][4];
  #pragma unroll
  for (int i = 0; i < 8; ++i)
    #pragma unroll
    for (int j = 0; j < 4; ++j) acc[i][j] = 0.0f;
  float4 kss = make_float4(0.f, 0.f, 0.f, 0.f);

  const int sbase = chunk * tiles * TS_;
  unsigned koff = (unsigned)((sbase + srow) * HD_ + scol);

  // prologue: K(0) first (older), then V(0) -> buf0
  float4 kreg = *(const float4*)(Kb + koff);
  __builtin_amdgcn_sched_barrier(0);
  gl_lds_16B(Vb + koff, &v_lds[0][w * 256]);

  #pragma unroll 1
  for (int t = 0; t < tiles; ++t) {
    // ---- A: stage K tile t (kreg consume waits K(t), leaves V(t) flying) --
    {
      float4 f;
      f.x = elu1(kreg.x); f.y = elu1(kreg.y); f.z = elu1(kreg.z); f.w = elu1(kreg.w);
      kss.x += f.x; kss.y += f.y; kss.z += f.z; kss.w += f.w;
      *(float4*)&fk_lds[srow * 64 + scolw] = f;
    }
    // ---- B: issue K(t+1) THEN V(t+1) (K must be the older op) -------------
    if (t + 1 < tiles) {
      koff += TS_ * HD_;
      kreg = *(const float4*)(Kb + koff);
      __builtin_amdgcn_sched_barrier(0);    // pin order: K before gl_lds V
      gl_lds_16B(Vb + koff, &v_lds[(t + 1) & 1][w * 256]);
    }
    // ---- W1: ds_write visible to block; V(t) landed; newer stay in flight -
    __builtin_amdgcn_sched_barrier(0);      // ds_write stays above
    asm volatile("s_waitcnt lgkmcnt(0)" ::: "memory");
    __builtin_amdgcn_s_barrier();
    if (t + 1 < tiles) asm volatile("s_waitcnt vmcnt(2)" ::: "memory");
    else               asm volatile("s_waitcnt vmcnt(0)" ::: "memory");
    __builtin_amdgcn_sched_barrier(0);      // compute stays below
    // ---- C: compute tile t -------------------------------------------------
    const float* vb = &v_lds[t & 1][0];
    #pragma unroll
    for (int g4 = 0; g4 < 8; ++g4) {
      const int s = g4 * 4 + sg;
      float4 vv = *(const float4*)&vb[s * 64 + eg * 4];
      const float* fr = &fk_lds[s * 64 + dswz];
      float4 k0 = *(const float4*)(fr + 0);
      float4 k1 = *(const float4*)(fr + 4);
      #define ACCROW(di, kc)                          \
        acc[di][0] = fmaf(kc, vv.x, acc[di][0]);      \
        acc[di][1] = fmaf(kc, vv.y, acc[di][1]);      \
        acc[di][2] = fmaf(kc, vv.z, acc[di][2]);      \
        acc[di][3] = fmaf(kc, vv.w, acc[di][3]);
      ACCROW(0, k0.x) ACCROW(1, k0.y) ACCROW(2, k0.z) ACCROW(3, k0.w)
      ACCROW(4, k1.x) ACCROW(5, k1.y) ACCROW(6, k1.z) ACCROW(7, k1.w)
      #undef ACCROW
    }
    // ---- W2: all reads of fk/v[t&1] done block-wide before next staging ----
    __builtin_amdgcn_sched_barrier(0);      // compute stays above
    __builtin_amdgcn_s_barrier();
  }

  // butterfly-reduce the 4-way s split (VALU permlanes)
  #pragma unroll
  for (int i = 0; i < 8; ++i)
    #pragma unroll
    for (int j = 0; j < 4; ++j)
      acc[i][j] = red32(red16(acc[i][j]));

  // plain coalesced stores of the block's partial 64x64 tile
  float* pkvb = pkv + ((size_t)chunk * NH_ + (size_t)(n * H_ + h)) * (D_ * E_);
  if (sg == 0) {
    #pragma unroll
    for (int i = 0; i < 8; ++i) {
      float4 o = make_float4(acc[i][0], acc[i][1], acc[i][2], acc[i][3]);
      *(float4*)&pkvb[(w * 8 + i) * E_ + eg * 4] = o;
    }
  }

  // partial Ksum: block-reduce in fk_lds (all fk reads done; vmem drained)
  __syncthreads();
  *(float4*)&fk_lds[srow * 64 + scol] = kss;
  __syncthreads();
  if (tid < 64) {
    float s = 0.f;
    #pragma unroll
    for (int r = 0; r < 32; ++r) s += fk_lds[r * 64 + tid];
    pks[((size_t)chunk * NH_ + (size_t)(n * H_ + h)) * D_ + tid] = s;
  }
}

// ---------------- reduce partials -> KV, Ksum ----------------
__global__ __launch_bounds__(256) void reduce_kv(const float* __restrict__ pkv,
                                                 const float* __restrict__ pks,
                                                 float* __restrict__ kvg,
                                                 float* __restrict__ ksg, int C) {
  const int nh = blockIdx.y;
  if (blockIdx.x < 16) {
    const int idx = blockIdx.x * 256 + threadIdx.x;
    float s = 0.f;
    #pragma unroll 1
    for (int c = 0; c < C; ++c)
      s += pkv[((size_t)c * NH_ + nh) * (D_ * E_) + idx];
    kvg[(size_t)nh * (D_ * E_) + idx] = s;
  } else if (threadIdx.x < 64) {
    float s = 0.f;
    #pragma unroll 1
    for (int c = 0; c < C; ++c)
      s += pks[((size_t)c * NH_ + nh) * D_ + threadIdx.x];
    ksg[(size_t)nh * D_ + threadIdx.x] = s;
  }
}

// ---------------- phase 2: out[l][e] = (fQ[l].KV[:,e]) * zden[l] -------------
// grid (L/64, H, N), block 256 (4 waves), wave handles 16 rows.
// Denominator computed DURING staging (each thread dots its float4 with
// Ksum[scol..+3], 16-lane xor-reduce, rcp stored to den_lds) -> main loop
// drops 16 FMA + 1 butterfly + ks[16] registers per row.
__global__ __launch_bounds__(256, 4) void p2_out(const float* __restrict__ queries,
                                                 const float* __restrict__ kvg,
                                                 const float* __restrict__ ksg,
                                                 float* __restrict__ out) {
  const int lt = blockIdx.x, h = blockIdx.y, n = blockIdx.z;
  const int tid = threadIdx.x;
  const int wave = tid >> 6, lane = tid & 63;
  const int dg = lane >> 4, eg = lane & 15;
  __shared__ float q_lds[64 * RS_];   // 17408 B
  __shared__ float den_lds[64];

  // KV sub-block: kv[di][ej] = KV[16dg+di][4eg+ej]
  const float* kvb = kvg + (size_t)(n * H_ + h) * (D_ * E_);
  float kv[16][4];
  #pragma unroll
  for (int i = 0; i < 16; ++i) {
    float4 t4 = *(const float4*)&kvb[(unsigned)(dg * 16 + i) * E_ + eg * 4];
    kv[i][0] = t4.x; kv[i][1] = t4.y; kv[i][2] = t4.z; kv[i][3] = t4.w;
  }

  // stage fQ tile [64][64] + fused per-row denominator
  const float* qb = queries + ((size_t)(n * L_ + lt * 64) * H_ + h) * D_;
  {
    const int srow = tid >> 4, scol = (tid & 15) * 4;
    const float4 ks4 = *(const float4*)(ksg + (size_t)(n * H_ + h) * D_ + scol);
    #pragma unroll
    for (int p = 0; p < 4; ++p) {
      const int r = p * 16 + srow;
      float4 q4 = *(const float4*)(qb + (unsigned)r * HD_ + scol);
      float4 f;
      f.x = elu1(q4.x); f.y = elu1(q4.y); f.z = elu1(q4.z); f.w = elu1(q4.w);
      *(float4*)&q_lds[r * RS_ + scol] = f;
      float dn = fmaf(f.x, ks4.x, fmaf(f.y, ks4.y, fmaf(f.z, ks4.z, f.w * ks4.w)));
      dn += __shfl_xor(dn, 1, 64);
      dn += __shfl_xor(dn, 2, 64);
      dn += __shfl_xor(dn, 4, 64);
      dn += __shfl_xor(dn, 8, 64);
      if ((tid & 15) == 0) {
#if __has_builtin(__builtin_amdgcn_rcpf)
        den_lds[r] = __builtin_amdgcn_rcpf(dn + EPS_);
#else
        den_lds[r] = 1.0f / (dn + EPS_);
#endif
      }
    }
  }
  __syncthreads();

  float* ob = out + ((size_t)(n * L_ + lt * 64) * H_ + h) * E_;
  float4 o4 = make_float4(0.f, 0.f, 0.f, 0.f);
  #pragma unroll 4
  for (int rr = 0; rr < 16; ++rr) {
    const int r = wave * 16 + rr;
    const float* qr = &q_lds[r * RS_ + dg * 16];
    float4 q0 = *(const float4*)(qr + 0);
    float4 q1 = *(const float4*)(qr + 4);
    float4 q2 = *(const float4*)(qr + 8);
    float4 q3 = *(const float4*)(qr + 12);
    const float z = den_lds[r];   // uniform broadcast b32
    float a0 = 0.f, a1 = 0.f, a2 = 0.f, a3 = 0.f;
    #define P2ACC(qc, i)                      \
      a0 = fmaf(qc, kv[i][0], a0);            \
      a1 = fmaf(qc, kv[i][1], a1);            \
      a2 = fmaf(qc, kv[i][2], a2);            \
      a3 = fmaf(qc, kv[i][3], a3);
    P2ACC(q0.x, 0)  P2ACC(q0.y, 1)  P2ACC(q0.z, 2)  P2ACC(q0.w, 3)
    P2ACC(q1.x, 4)  P2ACC(q1.y, 5)  P2ACC(q1.z, 6)  P2ACC(q1.w, 7)
    P2ACC(q2.x, 8)  P2ACC(q2.y, 9)  P2ACC(q2.z, 10) P2ACC(q2.w, 11)
    P2ACC(q3.x, 12) P2ACC(q3.y, 13) P2ACC(q3.z, 14) P2ACC(q3.w, 15)
    #undef P2ACC
    a0 = red32(red16(a0));
    a1 = red32(red16(a1));
    a2 = red32(red16(a2));
    a3 = red32(red16(a3));
    if (dg == (rr & 3)) { o4.x = a0 * z; o4.y = a1 * z; o4.z = a2 * z; o4.w = a3 * z; }
    if ((rr & 3) == 3) {   // full-wave 1 KiB store: lane (dg,eg) -> row base+dg
      const int rb = wave * 16 + (rr & ~3) + dg;
      *(float4*)(ob + (unsigned)rb * (H_ * E_) + eg * 4) = o4;
    }
  }
}

extern "C" void kernel_launch(void* const* d_in, const int* in_sizes, int n_in,
                              void* d_out, int out_size, void* d_ws, size_t ws_size,
                              hipStream_t stream) {
  const float* q = (const float*)d_in[0];
  const float* k = (const float*)d_in[1];
  const float* v = (const float*)d_in[2];
  float* outp = (float*)d_out;

  float* kvg = (float*)d_ws;                         // NH * 4096
  float* ksg = kvg + (size_t)NH_ * D_ * E_;          // NH * 64
  float* pkv = ksg + (size_t)NH_ * D_;               // C * NH * 4096
  int C = 32;
  while (C > 1) {
    size_t need = ((size_t)NH_ * D_ * E_ + (size_t)NH_ * D_ +
                   (size_t)C * NH_ * (D_ * E_ + D_)) * sizeof(float);
    if (need <= ws_size) break;
    C >>= 1;
  }
  float* pks = pkv + (size_t)C * NH_ * (D_ * E_);
  const int tiles = S_ / (C * TS_);

  hipLaunchKernelGGL(p1_kv, dim3(C, H_, N_), dim3(512), 0, stream, k, v, pkv, pks, tiles);
  hipLaunchKernelGGL(reduce_kv, dim3(17, NH_), dim3(256), 0, stream, pkv, pks, kvg, ksg, C);
  hipLaunchKernelGGL(p2_out, dim3(L_ / 64, H_, N_), dim3(256), 0, stream, q, kvg, ksg, outp);
}

// Round 10
// 86.017 us; speedup vs baseline: 1.8553x; 1.8553x over previous
//
#include <hip/hip_runtime.h>
#include <cstdint>

#define N_ 4
#define L_ 8192
#define S_ 8192
#define H_ 8
#define D_ 64
#define E_ 64
#define HD_ 512       // H_*D_ row stride in floats
#define NH_ 32        // N_*H_
#define EPS_ 1e-6f
#define TS_ 32        // s-rows per tile (p1)

typedef unsigned int u32;
typedef unsigned short u16;
typedef __attribute__((ext_vector_type(4))) float f32x4;
typedef __attribute__((ext_vector_type(8))) __bf16 bf16x8;

__device__ __forceinline__ float elu1(float x) {
  return x > 0.0f ? x + 1.0f : __expf(x);
}
// f32 pair -> packed bf16x2 (RNE), v_cvt_pk_bf16_f32 (no builtin on gfx950)
__device__ __forceinline__ u32 cvtpk(float a, float b) {
  u32 r;
  asm("v_cvt_pk_bf16_f32 %0, %1, %2" : "=v"(r) : "v"(a), "v"(b));
  return r;
}
__device__ __forceinline__ f32x4 mfma16(bf16x8 a, bf16x8 b, f32x4 c) {
  return __builtin_amdgcn_mfma_f32_16x16x32_bf16(a, b, c, 0, 0, 0);
}

// ---------------- phase 1 (MFMA): partial KV per chunk + partial Ksum -------
// grid (C=32, H, N), block 512 (8 waves). LDS 32 KiB: 2 buf x (fkT + vT), each
// 64 rows x 64 bf16 (128B rows, s-minor), XOR-swizzled ^(((row>>1)&7)<<4).
// Staging: thread (srow=tid>>4, scol4): loads K,V float4 -> elu(K) -> cvt_pk
// -> shfl_xor(16) partner (s^1) -> v_perm pairs -> even-s threads write 8 b32
// ([d][s-pair] / [e][s-pair]). Wave w: dd=w&3, ee={2*(w>>2), +1}; per tile:
// 3 ds_read_b128 (a,b0,b1) + 2 MFMA. One raw barrier + lgkmcnt(0) per tile;
// global prefetch regs carry across the barrier (auto counted vmcnt on use).
__global__ __launch_bounds__(512, 8) void p1_kv(const float* __restrict__ keys,
                                                const float* __restrict__ values,
                                                float* __restrict__ pkv,
                                                float* __restrict__ pks,
                                                int tiles) {
  const int chunk = blockIdx.x, h = blockIdx.y, n = blockIdx.z;
  const int tid = threadIdx.x, w = tid >> 6, lane = tid & 63;
  const int m = lane & 15, kb = lane >> 4;
  const int srow = tid >> 4, scol4 = (tid & 15) * 4;
  __shared__ u16 lds[16384];            // 32768 B
  char* base = (char*)lds;

  const int dd = w & 3, ee0 = (w >> 2) * 2;
  const int Ra = dd * 16 + m;
  const int aoff = (Ra * 128 + kb * 16) ^ (((Ra >> 1) & 7) << 4);
  const int Rb0 = ee0 * 16 + m, Rb1 = Rb0 + 16;
  const int b0off = ((Rb0 * 128 + kb * 16) ^ (((Rb0 >> 1) & 7) << 4)) + 8192;
  const int b1off = ((Rb1 * 128 + kb * 16) ^ (((Rb1 >> 1) & 7) << 4)) + 8192;
  int wo[4];
  #pragma unroll
  for (int j = 0; j < 4; ++j) {
    int R = scol4 + j;
    wo[j] = (R * 128 + (srow >> 1) * 4) ^ (((R >> 1) & 7) << 4);
  }
  const bool wr = !(srow & 1);          // even-s threads commit the pairs

  const float* Kb_ = keys   + (size_t)n * S_ * HD_ + h * D_;
  const float* Vb_ = values + (size_t)n * S_ * HD_ + h * D_;
  u32 goff = (u32)((chunk * tiles * TS_ + srow) * HD_ + scol4);

  f32x4 acc0 = {0.f, 0.f, 0.f, 0.f}, acc1 = {0.f, 0.f, 0.f, 0.f};
  float4 kss = make_float4(0.f, 0.f, 0.f, 0.f);

  float4 kA = *(const float4*)(Kb_ + goff);
  float4 vA = *(const float4*)(Vb_ + goff);
  float4 kB, vB;

#define STAGE(k4, v4, BUF)                                                     \
  {                                                                            \
    float4 f;                                                                  \
    f.x = elu1(k4.x); f.y = elu1(k4.y); f.z = elu1(k4.z); f.w = elu1(k4.w);    \
    kss.x += f.x; kss.y += f.y; kss.z += f.z; kss.w += f.w;                    \
    u32 kl = cvtpk(f.x, f.y), kh = cvtpk(f.z, f.w);                            \
    u32 vl = cvtpk(v4.x, v4.y), vh = cvtpk(v4.z, v4.w);                        \
    u32 pkl = (u32)__shfl_xor((int)kl, 16, 64);                                \
    u32 pkh = (u32)__shfl_xor((int)kh, 16, 64);                                \
    u32 pvl = (u32)__shfl_xor((int)vl, 16, 64);                                \
    u32 pvh = (u32)__shfl_xor((int)vh, 16, 64);                                \
    if (wr) {                                                                  \
      *(u32*)(base + (BUF) + wo[0]) = __builtin_amdgcn_perm(pkl, kl, 0x05040100u); \
      *(u32*)(base + (BUF) + wo[1]) = __builtin_amdgcn_perm(pkl, kl, 0x07060302u); \
      *(u32*)(base + (BUF) + wo[2]) = __builtin_amdgcn_perm(pkh, kh, 0x05040100u); \
      *(u32*)(base + (BUF) + wo[3]) = __builtin_amdgcn_perm(pkh, kh, 0x07060302u); \
      *(u32*)(base + (BUF) + 8192 + wo[0]) = __builtin_amdgcn_perm(pvl, vl, 0x05040100u); \
      *(u32*)(base + (BUF) + 8192 + wo[1]) = __builtin_amdgcn_perm(pvl, vl, 0x07060302u); \
      *(u32*)(base + (BUF) + 8192 + wo[2]) = __builtin_amdgcn_perm(pvh, vh, 0x05040100u); \
      *(u32*)(base + (BUF) + 8192 + wo[3]) = __builtin_amdgcn_perm(pvh, vh, 0x07060302u); \
    }                                                                          \
  }

#define COMPUTE(BUF)                                                           \
  {                                                                            \
    uint4 ar  = *(const uint4*)(base + (BUF) + aoff);                          \
    uint4 b0r = *(const uint4*)(base + (BUF) + b0off);                         \
    uint4 b1r = *(const uint4*)(base + (BUF) + b1off);                         \
    bf16x8 av = __builtin_bit_cast(bf16x8, ar);                                \
    acc0 = mfma16(av, __builtin_bit_cast(bf16x8, b0r), acc0);                  \
    acc1 = mfma16(av, __builtin_bit_cast(bf16x8, b1r), acc1);                  \
  }

  #pragma unroll 1
  for (int t = 0; t < tiles; t += 2) {
    STAGE(kA, vA, 0)
    { goff += TS_ * HD_;                       // tile t+1 (always exists)
      kB = *(const float4*)(Kb_ + goff);
      vB = *(const float4*)(Vb_ + goff); }
    asm volatile("s_waitcnt lgkmcnt(0)" ::: "memory");
    __builtin_amdgcn_s_barrier();
    COMPUTE(0)
    STAGE(kB, vB, 16384)
    if (t + 2 < tiles) { goff += TS_ * HD_;
      kA = *(const float4*)(Kb_ + goff);
      vA = *(const float4*)(Vb_ + goff); }
    asm volatile("s_waitcnt lgkmcnt(0)" ::: "memory");
    __builtin_amdgcn_s_barrier();
    COMPUTE(16384)
  }
#undef STAGE
#undef COMPUTE

  // partial KV stores: D[row=4*kb+r][col=m] per sub-tile (m89-verified layout)
  float* pkvb = pkv + ((size_t)chunk * NH_ + (size_t)(n * H_ + h)) * (D_ * E_);
  #pragma unroll
  for (int r = 0; r < 4; ++r) {
    pkvb[(dd * 16 + kb * 4 + r) * 64 + ee0 * 16 + m]       = acc0[r];
    pkvb[(dd * 16 + kb * 4 + r) * 64 + (ee0 + 1) * 16 + m] = acc1[r];
  }

  // partial Ksum block-reduce (reuse LDS as f32 scratch)
  __syncthreads();
  float* sc = (float*)lds;
  *(float4*)(sc + srow * 64 + scol4) = kss;
  __syncthreads();
  if (tid < 64) {
    float s = 0.f;
    #pragma unroll
    for (int r = 0; r < 32; ++r) s += sc[r * 64 + tid];
    pks[((size_t)chunk * NH_ + (size_t)(n * H_ + h)) * 64 + tid] = s;
  }
}

// ---------------- reduce: partials -> KVT bf16 [NH][80][64] ------------------
// rows 0..63 = KV^T (e-major, d-contiguous), row 64 = Ksum bf16, 65..79 = 0.
__global__ __launch_bounds__(256) void reduce_kv(const float* __restrict__ pkv,
                                                 const float* __restrict__ pks,
                                                 u16* __restrict__ kvt5, int C) {
  const int nh = blockIdx.x, tid = threadIdx.x;
  __shared__ float lds[64 * 65];
  float acc[16];
  #pragma unroll
  for (int k = 0; k < 16; ++k) acc[k] = 0.f;
  #pragma unroll 1
  for (int c = 0; c < C; ++c) {
    const float* p = pkv + ((size_t)c * NH_ + nh) * 4096;
    #pragma unroll
    for (int j = 0; j < 4; ++j) {
      float4 f = *(const float4*)(p + j * 1024 + tid * 4);
      acc[j * 4 + 0] += f.x; acc[j * 4 + 1] += f.y;
      acc[j * 4 + 2] += f.z; acc[j * 4 + 3] += f.w;
    }
  }
  #pragma unroll
  for (int j = 0; j < 4; ++j)
    #pragma unroll
    for (int k2 = 0; k2 < 4; ++k2)
      lds[(j * 16 + (tid >> 4)) * 65 + (tid & 15) * 4 + k2] = acc[j * 4 + k2];
  __syncthreads();
  {
    const int e = tid >> 2, d0 = (tid & 3) * 16;
    u32 pk8[8];
    #pragma unroll
    for (int q = 0; q < 8; ++q)
      pk8[q] = cvtpk(lds[(d0 + 2 * q) * 65 + e], lds[(d0 + 2 * q + 1) * 65 + e]);
    u16* dst = kvt5 + (size_t)nh * (80 * 64) + e * 64 + d0;
    *(uint4*)(dst)     = make_uint4(pk8[0], pk8[1], pk8[2], pk8[3]);
    *(uint4*)(dst + 8) = make_uint4(pk8[4], pk8[5], pk8[6], pk8[7]);
  }
  if (tid < 64) {
    float s = 0.f;
    #pragma unroll 1
    for (int c = 0; c < C; ++c) s += pks[((size_t)c * NH_ + nh) * 64 + tid];
    kvt5[(size_t)nh * (80 * 64) + 64 * 64 + tid] = (u16)(cvtpk(s, 0.f) & 0xffffu);
  }
  {
    u32* z = (u32*)(kvt5 + (size_t)nh * (80 * 64) + 65 * 64);
    for (int i = tid; i < 480; i += 256) z[i] = 0u;   // 15 rows x 64 bf16
  }
}

// ---------------- phase 2 (MFMA): out = (fQ x KV) * rcp(fQ.Ksum + eps) ------
// grid (64, H, N), block 256 (4 waves). NO LDS, NO barriers. A-frags (fQ)
// built in-register from global (Q rows are d-contiguous); B-frags (KVT +
// Ksum-aux column block) loaded once. 5th ee-block col0 = denominator.
__global__ __launch_bounds__(256, 4) void p2_out(const float* __restrict__ queries,
                                                 const u16* __restrict__ kvt5,
                                                 float* __restrict__ out) {
  const int lt = blockIdx.x, h = blockIdx.y, n = blockIdx.z;
  const int tid = threadIdx.x, w = tid >> 6, lane = tid & 63;
  const int m = lane & 15, kb = lane >> 4;
  const int nh = n * H_ + h;
  const u16* kp = kvt5 + (size_t)nh * (80 * 64);
  uint4 B[5][2];
  #pragma unroll
  for (int ee = 0; ee < 5; ++ee)
    #pragma unroll
    for (int ks = 0; ks < 2; ++ks)
      B[ee][ks] = *(const uint4*)(kp + (ee * 16 + m) * 64 + ks * 32 + kb * 8);

  #pragma unroll 1
  for (int rt = 0; rt < 2; ++rt) {
    const int rowbase = lt * 128 + rt * 64 + w * 16;
    const float* qp = queries + ((size_t)(n * L_ + rowbase + m) * H_ + h) * D_;
    float4 qa = *(const float4*)(qp + kb * 8);
    float4 qb_ = *(const float4*)(qp + kb * 8 + 4);
    float4 qc = *(const float4*)(qp + 32 + kb * 8);
    float4 qd = *(const float4*)(qp + 32 + kb * 8 + 4);
    uint4 a0r, a1r;
    a0r.x = cvtpk(elu1(qa.x), elu1(qa.y));  a0r.y = cvtpk(elu1(qa.z), elu1(qa.w));
    a0r.z = cvtpk(elu1(qb_.x), elu1(qb_.y)); a0r.w = cvtpk(elu1(qb_.z), elu1(qb_.w));
    a1r.x = cvtpk(elu1(qc.x), elu1(qc.y));  a1r.y = cvtpk(elu1(qc.z), elu1(qc.w));
    a1r.z = cvtpk(elu1(qd.x), elu1(qd.y));  a1r.w = cvtpk(elu1(qd.z), elu1(qd.w));
    bf16x8 a0 = __builtin_bit_cast(bf16x8, a0r);
    bf16x8 a1 = __builtin_bit_cast(bf16x8, a1r);
    f32x4 acc[5];
    #pragma unroll
    for (int ee = 0; ee < 5; ++ee) {
      acc[ee] = f32x4{0.f, 0.f, 0.f, 0.f};
      acc[ee] = mfma16(a0, __builtin_bit_cast(bf16x8, B[ee][0]), acc[ee]);
      acc[ee] = mfma16(a1, __builtin_bit_cast(bf16x8, B[ee][1]), acc[ee]);
    }
    float z[4];
    #pragma unroll
    for (int r = 0; r < 4; ++r) {
      float dn = __shfl(acc[4][r], lane & 48, 64);   // col0 of aux block
#if __has_builtin(__builtin_amdgcn_rcpf)
      z[r] = __builtin_amdgcn_rcpf(dn + EPS_);
#else
      z[r] = 1.0f / (dn + EPS_);
#endif
    }
    float* ob = out + ((size_t)(n * L_ + rowbase) * H_ + h) * E_;
    #pragma unroll
    for (int ee = 0; ee < 4; ++ee)
      #pragma unroll
      for (int r = 0; r < 4; ++r)
        ob[(size_t)(kb * 4 + r) * (H_ * E_) + ee * 16 + m] = acc[ee][r] * z[r];
  }
}

extern "C" void kernel_launch(void* const* d_in, const int* in_sizes, int n_in,
                              void* d_out, int out_size, void* d_ws, size_t ws_size,
                              hipStream_t stream) {
  const float* q = (const float*)d_in[0];
  const float* k = (const float*)d_in[1];
  const float* v = (const float*)d_in[2];
  float* outp = (float*)d_out;

  int C = 32;
  while (C > 1) {
    size_t need = ((size_t)C * NH_ * (4096 + 64)) * sizeof(float)
                + (size_t)NH_ * 80 * 64 * sizeof(u16);
    if (need <= ws_size) break;
    C >>= 1;
  }
  float* pkv = (float*)d_ws;                            // C*NH*4096 f32
  float* pks = pkv + (size_t)C * NH_ * 4096;            // C*NH*64 f32
  u16* kvt5 = (u16*)(pks + (size_t)C * NH_ * 64);       // NH*80*64 bf16
  const int tiles = S_ / (C * TS_);

  hipLaunchKernelGGL(p1_kv, dim3(C, H_, N_), dim3(512), 0, stream, k, v, pkv, pks, tiles);
  hipLaunchKernelGGL(reduce_kv, dim3(NH_), dim3(256), 0, stream, pkv, pks, kvt5, C);
  hipLaunchKernelGGL(p2_out, dim3(L_ / 128, H_, N_), dim3(256), 0, stream, q, kvt5, outp);
}